// Round 1
// baseline (189.829 us; speedup 1.0000x reference)
//
#include <hip/hip_runtime.h>
#include <hip/hip_bf16.h>

// out[e] = relu(z_student[row[e]]@W1_top + z_course[col[e]]@W1_bot + b1) @ W2 + b2
// Restructured: u_s = z_s@W1_top (+0), u_c = z_c@W1_bot; per edge:
// out = sum_k relu(u_s[row][k]+u_c[col][k]+b1[k]) * W2[k] + b2.
// u_s/u_c stored bf16 in workspace (halves gather bytes; error << threshold).

typedef __attribute__((ext_vector_type(8))) short short8;
typedef __attribute__((ext_vector_type(4))) float float4v;

static __device__ __forceinline__ unsigned short f32_to_bf16(float f) {
    union { float f; unsigned u; } v; v.f = f;
    unsigned r = v.u + 0x7fffu + ((v.u >> 16) & 1u);   // round-to-nearest-even
    return (unsigned short)(r >> 16);
}
static __device__ __forceinline__ float bf16_lo(unsigned u) {
    union { unsigned u; float f; } v; v.u = u << 16; return v.f;
}
static __device__ __forceinline__ float bf16_hi(unsigned u) {
    union { unsigned u; float f; } v; v.u = u & 0xffff0000u; return v.f;
}

// ---- Kernel 1: transpose+cast W1 [256,128] fp32 -> Wt[half][n][k] bf16 ----
__global__ void conv_w_kernel(const float* __restrict__ W1, unsigned short* __restrict__ Wt) {
    int id = blockIdx.x * 256 + threadIdx.x;           // 32768 total
    int h = id >> 14;                                   // which half of W1
    int n = (id >> 7) & 127;                            // output-feature
    int k = id & 127;                                   // input-feature
    Wt[id] = f32_to_bf16(W1[(h * 128 + k) * 128 + n]);
}

// ---- Kernel 2: U[M,128] = bf16( Z[M,128] @ W(+b1) ), MFMA 16x16x32 bf16 ----
#define LDSPITCH 136   // 128 + 8 bf16 pad -> 2-way (free) LDS conflicts on b128 reads
__global__ __launch_bounds__(256) void gemm_u_kernel(
    const float* __restrict__ Z, const unsigned short* __restrict__ Wt,
    const float* __restrict__ b1, unsigned short* __restrict__ U,
    int M, int addB)
{
    __shared__ __align__(16) unsigned short lds[128 * LDSPITCH];
    const int tid = threadIdx.x;

    // Stage Wt (already [n][k] bf16, contiguous) into padded LDS, 16B chunks.
    for (int i = 0; i < 8; ++i) {
        int j = tid + i * 256;                 // uint4 index, 2048 total
        int n = j >> 4, chunk = j & 15;
        uint4 v = ((const uint4*)Wt)[j];
        *((uint4*)&lds[n * LDSPITCH + chunk * 8]) = v;
    }
    __syncthreads();

    const int wave = tid >> 6, lane = tid & 63;
    const int quad = lane >> 4, l16 = lane & 15;
    long mrow = (long)blockIdx.x * 64 + wave * 16 + l16;
    long mload = mrow < M ? mrow : (long)(M - 1);      // clamp; stores guarded
    const float* zrow = Z + mload * 128;

    float4v acc[8];
    for (int nt = 0; nt < 8; ++nt) acc[nt] = (float4v)(0.0f);

    for (int c = 0; c < 4; ++c) {                      // K chunks of 32
        const float4* pa = (const float4*)(zrow + c * 32 + quad * 8);
        float4 a0 = pa[0], a1 = pa[1];
        short8 afrag;
        afrag[0] = (short)f32_to_bf16(a0.x); afrag[1] = (short)f32_to_bf16(a0.y);
        afrag[2] = (short)f32_to_bf16(a0.z); afrag[3] = (short)f32_to_bf16(a0.w);
        afrag[4] = (short)f32_to_bf16(a1.x); afrag[5] = (short)f32_to_bf16(a1.y);
        afrag[6] = (short)f32_to_bf16(a1.z); afrag[7] = (short)f32_to_bf16(a1.w);
        for (int nt = 0; nt < 8; ++nt) {
            const short8* pb = (const short8*)&lds[(nt * 16 + l16) * LDSPITCH + c * 32 + quad * 8];
            acc[nt] = __builtin_amdgcn_mfma_f32_16x16x32_bf16(afrag, *pb, acc[nt], 0, 0, 0);
        }
    }

    // C layout (16x16x32): col = lane&15, row = quad*4 + reg
    long rbase = (long)blockIdx.x * 64 + wave * 16 + quad * 4;
    for (int nt = 0; nt < 8; ++nt) {
        int n = nt * 16 + l16;
        float bv = addB ? b1[n] : 0.0f;
        for (int r = 0; r < 4; ++r) {
            long rr = rbase + r;
            if (rr < M) U[rr * 128 + n] = f32_to_bf16(acc[nt][r] + bv);
        }
    }
}

// ---- Kernel 3: per-edge gather + relu-dot, 16 lanes/edge, 16B/lane ----
__global__ __launch_bounds__(256) void edge_kernel(
    const int* __restrict__ row, const int* __restrict__ col,
    const unsigned short* __restrict__ us, const unsigned short* __restrict__ uc,
    const float* __restrict__ w2, const float* __restrict__ b2,
    float* __restrict__ out, int E)
{
    const int tid = threadIdx.x;
    const int sub = tid & 15;
    long e = (long)blockIdx.x * 16 + (tid >> 4);
    if (e >= E) return;
    int r = row[e], c = col[e];

    uint4 av = *(const uint4*)(us + (long)r * 128 + sub * 8);
    uint4 bv = *(const uint4*)(uc + (long)c * 128 + sub * 8);
    const float4* pw = (const float4*)(w2 + sub * 8);
    float4 w0 = pw[0], w1 = pw[1];

    float a[8] = { bf16_lo(av.x), bf16_hi(av.x), bf16_lo(av.y), bf16_hi(av.y),
                   bf16_lo(av.z), bf16_hi(av.z), bf16_lo(av.w), bf16_hi(av.w) };
    float b[8] = { bf16_lo(bv.x), bf16_hi(bv.x), bf16_lo(bv.y), bf16_hi(bv.y),
                   bf16_lo(bv.z), bf16_hi(bv.z), bf16_lo(bv.w), bf16_hi(bv.w) };
    float w[8] = { w0.x, w0.y, w0.z, w0.w, w1.x, w1.y, w1.z, w1.w };

    float s = 0.0f;
    #pragma unroll
    for (int j = 0; j < 8; ++j) {
        float h = a[j] + b[j];
        h = h > 0.0f ? h : 0.0f;
        s += h * w[j];
    }
    s += __shfl_xor(s, 1);
    s += __shfl_xor(s, 2);
    s += __shfl_xor(s, 4);
    s += __shfl_xor(s, 8);
    if (sub == 0) out[e] = s + b2[0];
}

extern "C" void kernel_launch(void* const* d_in, const int* in_sizes, int n_in,
                              void* d_out, int out_size, void* d_ws, size_t ws_size,
                              hipStream_t stream) {
    const float* zs  = (const float*)d_in[0];
    const float* zc  = (const float*)d_in[1];
    const int*   row = (const int*)d_in[2];
    const int*   col = (const int*)d_in[3];
    const float* W1  = (const float*)d_in[4];
    const float* b1  = (const float*)d_in[5];
    const float* W2  = (const float*)d_in[6];
    const float* b2  = (const float*)d_in[7];
    float* out = (float*)d_out;

    const int Ms = in_sizes[0] / 128;   // 100000
    const int Mc = in_sizes[1] / 128;   // 20000
    const int E  = in_sizes[2];         // 1000000

    unsigned short* Wt = (unsigned short*)d_ws;                       // 2*128*128 bf16 = 64 KiB
    unsigned short* us = (unsigned short*)((char*)d_ws + 65536);      // Ms*128 bf16
    unsigned short* uc = us + (size_t)Ms * 128;                       // Mc*128 bf16

    conv_w_kernel<<<128, 256, 0, stream>>>(W1, Wt);
    gemm_u_kernel<<<(Ms + 63) / 64, 256, 0, stream>>>(zs, Wt,         b1, us, Ms, 1);
    gemm_u_kernel<<<(Mc + 63) / 64, 256, 0, stream>>>(zc, Wt + 16384, b1, uc, Mc, 0);
    edge_kernel<<<(E + 15) / 16, 256, 0, stream>>>(row, col, us, uc, W2, b2, out, E);
}

// Round 3
// 169.606 us; speedup vs baseline: 1.1192x; 1.1192x over previous
//
#include <hip/hip_runtime.h>
#include <hip/hip_bf16.h>
#include <hip/hip_fp16.h>

// out[e] = relu(z_s[row[e]]@W1_top + z_c[col[e]]@W1_bot + b1) @ W2 + b2
// u_s = z_s@W1_top + b1, u_c = z_c@W1_bot (both f16 in ws); per edge:
// out = sum_k relu(u_s[row][k]+u_c[col][k]) * W2[k] + b2.

typedef _Float16 half2v __attribute__((ext_vector_type(2)));
typedef _Float16 half8v __attribute__((ext_vector_type(8)));
typedef __fp16   fp16x2 __attribute__((ext_vector_type(2)));
typedef float    float4v __attribute__((ext_vector_type(4)));

// ---- Kernel 1: W1 [256,128] fp32 -> Wt[half][n][k] f16 (LDS transpose), W2 -> f16 ----
__global__ __launch_bounds__(256) void conv_w(const float* __restrict__ W1,
                                              const float* __restrict__ W2,
                                              _Float16* __restrict__ Wt,
                                              _Float16* __restrict__ w2h) {
    int b = blockIdx.x, t = threadIdx.x;
    if (b == 8) { if (t < 128) w2h[t] = (_Float16)W2[t]; return; }
    __shared__ _Float16 lds[32][136];
    int h = b >> 2, n0 = (b & 3) * 32;
    for (int i = 0; i < 16; ++i) {
        int idx = i * 256 + t;            // 4096 = 128k x 32n
        int k = idx >> 5, nn = idx & 31;
        lds[nn][k] = (_Float16)W1[(h * 128 + k) * 128 + n0 + nn];
    }
    __syncthreads();
    for (int j = 0; j < 2; ++j) {
        int idx = j * 256 + t;            // 512 = 32n x 16 chunks
        int nn = idx >> 4, kc = idx & 15;
        half8v v;
        #pragma unroll
        for (int q = 0; q < 8; ++q) v[q] = lds[nn][kc * 8 + q];
        *(half8v*)&Wt[((h * 128 + n0 + nn) * 128) + kc * 8] = v;
    }
}

// ---- Kernel 2: fused U_s / U_c GEMM, MFMA 16x16x32 f16, vectorized epilogue ----
// LDS layout: row n (128 rows), 16 chunks of 16B, chunk slot = ch ^ ((n>>3)&7)
// -> B-frag ds_read_b128 lands 2-way bank aliased (free).
__global__ __launch_bounds__(256) void gemm_u(
    const float* __restrict__ Zs, const float* __restrict__ Zc,
    const _Float16* __restrict__ Wt, const float* __restrict__ b1,
    _Float16* __restrict__ Us, _Float16* __restrict__ Uc,
    int Ms, int Mc, int nbs)
{
    __shared__ uint4 ldsW[2048];          // 128 x 16 chunks, swizzled, 32 KiB
    const int bid = blockIdx.x, t = threadIdx.x;

    const float* Z; _Float16* U; const _Float16* W; int M, m0, addB;
    if (bid < nbs) { Z = Zs; U = Us; M = Ms; m0 = bid * 64;         W = Wt;         addB = 1; }
    else           { Z = Zc; U = Uc; M = Mc; m0 = (bid - nbs) * 64; W = Wt + 16384; addB = 0; }

    const uint4* Wv = (const uint4*)W;    // [n][16 chunks]
    #pragma unroll
    for (int i = 0; i < 8; ++i) {
        int j = i * 256 + t;              // 2048
        int n = j >> 4, ch = j & 15;
        ldsW[n * 16 + (ch ^ ((n >> 3) & 7))] = Wv[j];
    }
    __syncthreads();

    const int wave = t >> 6, lane = t & 63, quad = lane >> 4, l16 = lane & 15;
    int mrow = m0 + wave * 16 + l16;
    int mload = mrow < M ? mrow : M - 1;  // clamp; stores guarded
    const float* zrow = Z + (long)mload * 128;

    float4v acc[8];
    #pragma unroll
    for (int nt = 0; nt < 8; ++nt) acc[nt] = (float4v)(0.0f);

    #pragma unroll
    for (int c = 0; c < 4; ++c) {
        const float4v* pa = (const float4v*)(zrow + c * 32 + quad * 8);
        float4v a0 = pa[0], a1 = pa[1];
        fp16x2 p[4];
        p[0] = __builtin_amdgcn_cvt_pkrtz(a0[0], a0[1]);
        p[1] = __builtin_amdgcn_cvt_pkrtz(a0[2], a0[3]);
        p[2] = __builtin_amdgcn_cvt_pkrtz(a1[0], a1[1]);
        p[3] = __builtin_amdgcn_cvt_pkrtz(a1[2], a1[3]);
        half8v af;
        __builtin_memcpy(&af, &p[0], 16);
        const int ch = c * 4 + quad;
        #pragma unroll
        for (int nt = 0; nt < 8; ++nt) {
            // MFMA #nt computes actual col n = l16*8 + nt at frag-col l16
            const int n = l16 * 8 + nt;
            const half8v* pb = (const half8v*)&ldsW[n * 16 + (ch ^ (l16 & 7))];
            acc[nt] = __builtin_amdgcn_mfma_f32_16x16x32_f16(af, *pb, acc[nt], 0, 0, 0);
        }
    }

    float bv[8];
    if (addB) {
        const float4v* pb1 = (const float4v*)(b1 + l16 * 8);
        float4v x0 = pb1[0], x1 = pb1[1];
        bv[0]=x0[0]; bv[1]=x0[1]; bv[2]=x0[2]; bv[3]=x0[3];
        bv[4]=x1[0]; bv[5]=x1[1]; bv[6]=x1[2]; bv[7]=x1[3];
    } else {
        #pragma unroll
        for (int i = 0; i < 8; ++i) bv[i] = 0.0f;
    }

    // C layout: frag-col = l16 -> actual cols l16*8+0..7 contiguous -> 16B stores
    const int rbase = m0 + wave * 16 + quad * 4;
    #pragma unroll
    for (int r = 0; r < 4; ++r) {
        int rr = rbase + r;
        if (rr < M) {
            half8v o;
            #pragma unroll
            for (int nt = 0; nt < 8; ++nt) o[nt] = (_Float16)(acc[nt][r] + bv[nt]);
            *(half8v*)&U[(long)rr * 128 + l16 * 8] = o;
        }
    }
}

// ---- Kernel 3: gather + relu-dot, 8 lanes/edge, 32B/lane/side, pk f16 math ----
__global__ __launch_bounds__(256) void edge_kernel(
    const int* __restrict__ row, const int* __restrict__ col,
    const _Float16* __restrict__ us, const _Float16* __restrict__ uc,
    const _Float16* __restrict__ w2h, const float* __restrict__ b2,
    float* __restrict__ out, int E)
{
    const int t = threadIdx.x;
    const int sub = t & 7;
    long e = (long)blockIdx.x * 32 + (t >> 3);
    if (e >= E) return;
    int r = row[e], c = col[e];

    const uint4* pa = (const uint4*)(us  + (long)r * 128 + sub * 16);
    const uint4* pb = (const uint4*)(uc  + (long)c * 128 + sub * 16);
    const uint4* pw = (const uint4*)(w2h + sub * 16);
    uint4 a0 = pa[0], a1 = pa[1];
    uint4 c0 = pb[0], c1 = pb[1];
    uint4 w0 = pw[0], w1 = pw[1];

    half2v A[8], B[8], W[8];
    *(uint4*)&A[0] = a0; *(uint4*)&A[4] = a1;
    *(uint4*)&B[0] = c0; *(uint4*)&B[4] = c1;
    *(uint4*)&W[0] = w0; *(uint4*)&W[4] = w1;

    const half2v zero = {(_Float16)0, (_Float16)0};
    float s = 0.0f;
    #pragma unroll
    for (int i = 0; i < 8; ++i) {
        half2v h = A[i] + B[i];                       // v_pk_add_f16
        h = __builtin_elementwise_max(h, zero);       // v_pk_max_f16
        s += (float)h[0] * (float)W[i][0];            // v_fma mix / dot2
        s += (float)h[1] * (float)W[i][1];
    }
    s += __shfl_xor(s, 1);
    s += __shfl_xor(s, 2);
    s += __shfl_xor(s, 4);
    if (sub == 0) out[e] = s + b2[0];
}

extern "C" void kernel_launch(void* const* d_in, const int* in_sizes, int n_in,
                              void* d_out, int out_size, void* d_ws, size_t ws_size,
                              hipStream_t stream) {
    const float* zs  = (const float*)d_in[0];
    const float* zc  = (const float*)d_in[1];
    const int*   row = (const int*)d_in[2];
    const int*   col = (const int*)d_in[3];
    const float* W1  = (const float*)d_in[4];
    const float* b1  = (const float*)d_in[5];
    const float* W2  = (const float*)d_in[6];
    const float* b2  = (const float*)d_in[7];
    float* out = (float*)d_out;

    const int Ms = in_sizes[0] / 128;   // 100000
    const int Mc = in_sizes[1] / 128;   // 20000
    const int E  = in_sizes[2];         // 1000000

    _Float16* Wt  = (_Float16*)d_ws;                           // 2*128*128 f16 = 64 KiB
    _Float16* w2h = (_Float16*)((char*)d_ws + 65536);          // 128 f16
    _Float16* us  = (_Float16*)((char*)d_ws + 65536 + 256);    // Ms*128 f16
    _Float16* uc  = us + (size_t)Ms * 128;                     // Mc*128 f16

    const int nbs = (Ms + 63) / 64, nbc = (Mc + 63) / 64;

    conv_w<<<9, 256, 0, stream>>>(W1, W2, Wt, w2h);
    gemm_u<<<nbs + nbc, 256, 0, stream>>>(zs, zc, Wt, b1, us, uc, Ms, Mc, nbs);
    edge_kernel<<<(E + 31) / 32, 256, 0, stream>>>(row, col, us, uc, w2h, b2, out, E);
}